// Round 12
// baseline (296.510 us; speedup 1.0000x reference)
//
#include <hip/hip_runtime.h>

#define BB 16
#define KD 128
#define ND 8000
#define DD 256
#define LMB 1000.0f

typedef __attribute__((ext_vector_type(8))) short bf16x8;
typedef __attribute__((ext_vector_type(4))) short bf16x4;
typedef __attribute__((ext_vector_type(4))) float f32x4;
typedef unsigned short ushort_t;

// RNE split for gram (small data, per-element)
__device__ __forceinline__ void split_bf16_rne(float x, ushort_t& h, ushort_t& l) {
    unsigned int bi = __float_as_uint(x);
    h = (ushort_t)(bi >> 16);
    float lo = x - __uint_as_float(bi & 0xFFFF0000u);
    unsigned int lb = __float_as_uint(lo);
    lb = lb + 0x7FFFu + ((lb >> 16) & 1u);
    l = (ushort_t)(lb >> 16);
}

// async global->LDS, 16B per lane, lds dest = uniform base + lane*16
__device__ __forceinline__ void gll16(const float* g, float* l) {
    __builtin_amdgcn_global_load_lds(
        (const __attribute__((address_space(1))) void*)g,
        (__attribute__((address_space(3))) void*)l, 16, 0, 0);
}

// ---------------- K1: projection  sd[b][k][d] = sum_n pinv[b][k][n]*descr[b][d][n]
// R9 skeleton (gll16 fp32 async staging, fp32 dbuf, counted vmcnt(3), 8-slice
// chunk interleave c = s + 8t over 250 chunks) + DEDICATED CONVERT PHASE:
// each staged element is split to bf16 hi/lo exactly ONCE (v_perm_b32 packing,
// ~3 VALU/elem) into single-buffered bf16 LDS planes; the MFMA phase then reads
// pure bf16 fragments (12 x b128/wave, zero VALU, conflict-free: each wave's
// fragment set covers a contiguous 1KB row-range). No swizzle needed anywhere.
// LDS: 2x48KB fp32 + 2x24KB bf16 = 144KB, 1 block/CU. 3 barriers/chunk.
#define ROWS 384      // KD + DD
#define CHF 32        // chunk width in floats (K=32 per chunk)
#define NSL 8
#define SBUF_FL 12288 // ROWS*CHF

__global__ __attribute__((amdgpu_flat_work_group_size(1024, 1024)))
void proj_kernel(
    const float* __restrict__ pinv_a, const float* __restrict__ descr_a,
    const float* __restrict__ pinv_b, const float* __restrict__ descr_b,
    float* __restrict__ sd_a, float* __restrict__ sd_b)
{
    const int b = blockIdx.x, which = blockIdx.y, s = blockIdx.z;
    const float* P  = (which ? pinv_b  : pinv_a)  + (size_t)b * KD * ND;
    const float* Dm = (which ? descr_b : descr_a) + (size_t)b * DD * ND;
    float* outp = (which ? sd_b : sd_a) + (size_t)b * KD * DD;

    __shared__ float Sbuf[2][SBUF_FL];
    __shared__ ushort_t Hb[SBUF_FL];
    __shared__ ushort_t Lb[SBUF_FL];

    const int tid = threadIdx.x;
    const int lane = tid & 63;
    const int wid = tid >> 6;                 // 0..15
    const int wm = wid >> 2, wn = wid & 3;    // wave tile: rows wm*32, cols wn*64
    const int fr = lane & 15;
    const int kg = lane >> 4;
    const int NC = (s < 2) ? 32 : 31;         // chunks c = s + 8*t, c in [0,250)

    // staging: 48 wave-instrs of 1KB; instr I = wid*3+u covers rows [I*8, I*8+8)
    // lane: row = I*8 + (lane>>3), slot = lane&7 (16B units). Linear, no swizzle.
    const float* gp[3];
    int lof[3];
    #pragma unroll
    for (int u = 0; u < 3; ++u) {
        int I = wid * 3 + u;
        int r = I * 8 + (lane >> 3);
        const float* rowp = (r < KD) ? (P + (size_t)r * ND) : (Dm + (size_t)(r - KD) * ND);
        gp[u] = rowp + (lane & 7) * 4;
        lof[u] = I * 256;
    }

    f32x4 acc[2][4];
    #pragma unroll
    for (int i = 0; i < 2; ++i)
        #pragma unroll
        for (int j = 0; j < 4; ++j) acc[i][j] = (f32x4){0.f, 0.f, 0.f, 0.f};

    // prologue: stage chunk s -> buf 0
    #pragma unroll
    for (int u = 0; u < 3; ++u) gll16(gp[u] + s * CHF, &Sbuf[0][lof[u]]);

    for (int t = 0; t < NC; ++t) {
        const int buf = t & 1;
        if (t + 1 < NC) {
            const int noff = (s + NSL * (t + 1)) * CHF;
            #pragma unroll
            for (int u = 0; u < 3; ++u) gll16(gp[u] + noff, &Sbuf[buf ^ 1][lof[u]]);
            __builtin_amdgcn_sched_barrier(0);
            asm volatile("s_waitcnt vmcnt(3)" ::: "memory");   // wait chunk t only
        } else {
            __builtin_amdgcn_sched_barrier(0);
            asm volatile("s_waitcnt vmcnt(0)" ::: "memory");
        }
        __builtin_amdgcn_sched_barrier(0);
        __builtin_amdgcn_s_barrier();                          // fp32 chunk t ready
        __builtin_amdgcn_sched_barrier(0);

        // ---- convert phase: 12288 floats, once each; perm-packed hi/lo
        const float* base = &Sbuf[buf][0];
        #pragma unroll
        for (int p = 0; p < 3; ++p) {
            const int fi = p * 4096 + tid * 4;
            f32x4 v = *(const f32x4*)(base + fi);
            unsigned bx = __float_as_uint(v[0]), by = __float_as_uint(v[1]);
            unsigned bz = __float_as_uint(v[2]), bw = __float_as_uint(v[3]);
            uint2 h, l;
            h.x = __builtin_amdgcn_perm(by, bx, 0x07060302u);  // [hi(v1),hi(v0)]
            h.y = __builtin_amdgcn_perm(bw, bz, 0x07060302u);
            float lx = v[0] - __uint_as_float(bx & 0xFFFF0000u);
            float ly = v[1] - __uint_as_float(by & 0xFFFF0000u);
            float lz = v[2] - __uint_as_float(bz & 0xFFFF0000u);
            float lw = v[3] - __uint_as_float(bw & 0xFFFF0000u);
            l.x = __builtin_amdgcn_perm(__float_as_uint(ly), __float_as_uint(lx), 0x07060302u);
            l.y = __builtin_amdgcn_perm(__float_as_uint(lw), __float_as_uint(lz), 0x07060302u);
            *(uint2*)&Hb[fi] = h;
            *(uint2*)&Lb[fi] = l;
        }
        asm volatile("s_waitcnt lgkmcnt(0)" ::: "memory");     // writes visible
        __builtin_amdgcn_sched_barrier(0);
        __builtin_amdgcn_s_barrier();                          // bf16 planes ready
        __builtin_amdgcn_sched_barrier(0);

        // ---- MFMA phase: pure bf16 fragment reads, zero VALU
        bf16x8 Ah[2], Al[2];
        #pragma unroll
        for (int mi = 0; mi < 2; ++mi) {
            const int rA = wm * 32 + mi * 16 + fr;
            Ah[mi] = *(const bf16x8*)&Hb[rA * 32 + kg * 8];
            Al[mi] = *(const bf16x8*)&Lb[rA * 32 + kg * 8];
        }
        #pragma unroll
        for (int ni = 0; ni < 4; ++ni) {
            const int rB = KD + wn * 64 + ni * 16 + fr;
            bf16x8 Bh = *(const bf16x8*)&Hb[rB * 32 + kg * 8];
            bf16x8 Bl = *(const bf16x8*)&Lb[rB * 32 + kg * 8];
            #pragma unroll
            for (int mi = 0; mi < 2; ++mi) {
                acc[mi][ni] = __builtin_amdgcn_mfma_f32_16x16x32_bf16(Ah[mi], Bh, acc[mi][ni], 0, 0, 0);
                acc[mi][ni] = __builtin_amdgcn_mfma_f32_16x16x32_bf16(Ah[mi], Bl, acc[mi][ni], 0, 0, 0);
                acc[mi][ni] = __builtin_amdgcn_mfma_f32_16x16x32_bf16(Al[mi], Bh, acc[mi][ni], 0, 0, 0);
            }
        }
        __builtin_amdgcn_sched_barrier(0);
        __builtin_amdgcn_s_barrier();       // MFMA reads done before next convert
    }

    // epilogue: C/D layout col=lane&15, row=(lane>>4)*4+reg (m89)
    #pragma unroll
    for (int mi = 0; mi < 2; ++mi)
        #pragma unroll
        for (int ni = 0; ni < 4; ++ni) {
            int rbase = wm * 32 + mi * 16 + kg * 4;
            int ccol  = wn * 64 + ni * 16 + fr;
            #pragma unroll
            for (int r = 0; r < 4; ++r)
                atomicAdd(&outp[(size_t)(rbase + r) * DD + ccol], acc[mi][ni][r]);
        }
}

// ---------------- K2: masks (lambda folded in)
__global__ __launch_bounds__(256) void mask_kernel(
    const float* __restrict__ ea_g, const float* __restrict__ eb_g,
    float* __restrict__ lm_ab, float* __restrict__ lm_ba)
{
    const int b = blockIdx.x, tid = threadIdx.x;
    __shared__ float ta[KD], ua[KD], tb[KD], ub[KD];
    __shared__ float red[256];
    float e = (tid < KD) ? ea_g[b * KD + tid] : eb_g[b * KD + (tid - KD)];
    red[tid] = e;
    __syncthreads();
    for (int s = 128; s > 0; s >>= 1) {
        if (tid < s) red[tid] = fmaxf(red[tid], red[tid + s]);
        __syncthreads();
    }
    float is = 1.0f / red[0];
    float g = e * is;
    float den = 1.0f / (g * g + 1.0f);
    if (tid < KD) { ta[tid] = g * den; ua[tid] = den; }
    else          { tb[tid - KD] = g * den; ub[tid - KD] = den; }
    __syncthreads();
    for (int idx = tid; idx < KD * KD; idx += 256) {
        int i = idx >> 7, kc = idx & 127;
        float re = tb[i] - ta[kc], im = ub[i] - ua[kc];
        lm_ab[(size_t)b * KD * KD + idx] = LMB * (re * re + im * im);
        float re2 = ta[i] - tb[kc], im2 = ua[i] - ub[kc];
        lm_ba[(size_t)b * KD * KD + idx] = LMB * (re2 * re2 + im2 * im2);
    }
}

// ---------------- K3: Grams via split-bf16 MFMA, d-split for parallelism.
#define GSTR 68
__global__ __launch_bounds__(512, 2) void gram_kernel(
    const float* __restrict__ sd_a, const float* __restrict__ sd_b,
    float* __restrict__ AA)
{
    const int b = blockIdx.x, m = blockIdx.y, dchunk = blockIdx.z;
    const float* X = (m == 0) ? sd_a : sd_b;
    const float* Y = (m == 2) ? sd_a : X;
    X += (size_t)b * KD * DD;
    Y += (size_t)b * KD * DD;
    float* outp = AA + ((size_t)m * BB + b) * KD * KD;
    const int d0 = dchunk * 64;

    __shared__ ushort_t Xh[KD][GSTR], Xl[KD][GSTR];
    __shared__ ushort_t Yh[KD][GSTR], Yl[KD][GSTR];

    const int tid = threadIdx.x;
    const int lane = tid & 63;
    const int wid = tid >> 6;
    const int wm = wid >> 2, wn = wid & 3;
    const int fr = lane & 15;
    const int kg = lane >> 4;

    f32x4 acc[4][2];
    #pragma unroll
    for (int i = 0; i < 4; ++i)
        #pragma unroll
        for (int j = 0; j < 2; ++j) acc[i][j] = (f32x4){0.f, 0.f, 0.f, 0.f};

    #pragma unroll
    for (int u = 0; u < 8; ++u) {
        int idx = tid + (u & 3) * 512;
        int r = idx >> 4, c4 = idx & 15;
        const float* src = (u < 4) ? X : Y;
        float4 v = *(const float4*)(src + (size_t)r * DD + d0 + c4 * 4);
        float xs[4] = {v.x, v.y, v.z, v.w};
        bf16x4 hv, lv;
        #pragma unroll
        for (int q = 0; q < 4; ++q) {
            ushort_t hh, ll;
            split_bf16_rne(xs[q], hh, ll);
            hv[q] = (short)hh; lv[q] = (short)ll;
        }
        if (u < 4) {
            *(bf16x4*)&Xh[r][c4 * 4] = hv;
            *(bf16x4*)&Xl[r][c4 * 4] = lv;
        } else {
            *(bf16x4*)&Yh[r][c4 * 4] = hv;
            *(bf16x4*)&Yl[r][c4 * 4] = lv;
        }
    }
    __syncthreads();

    #pragma unroll
    for (int kk = 0; kk < 2; ++kk) {
        const int co = kk * 32 + kg * 8;
        bf16x8 Ah[4], Al[4];
        #pragma unroll
        for (int mi = 0; mi < 4; ++mi) {
            int r = wm * 64 + mi * 16 + fr;
            Ah[mi] = *(const bf16x8*)&Xh[r][co];
            Al[mi] = *(const bf16x8*)&Xl[r][co];
        }
        #pragma unroll
        for (int ni = 0; ni < 2; ++ni) {
            int c = wn * 32 + ni * 16 + fr;
            bf16x8 Bh = *(const bf16x8*)&Yh[c][co];
            bf16x8 Bl = *(const bf16x8*)&Yl[c][co];
            #pragma unroll
            for (int mi = 0; mi < 4; ++mi) {
                acc[mi][ni] = __builtin_amdgcn_mfma_f32_16x16x32_bf16(Ah[mi], Bh, acc[mi][ni], 0, 0, 0);
                acc[mi][ni] = __builtin_amdgcn_mfma_f32_16x16x32_bf16(Ah[mi], Bl, acc[mi][ni], 0, 0, 0);
                acc[mi][ni] = __builtin_amdgcn_mfma_f32_16x16x32_bf16(Al[mi], Bh, acc[mi][ni], 0, 0, 0);
            }
        }
    }

    #pragma unroll
    for (int mi = 0; mi < 4; ++mi)
        #pragma unroll
        for (int ni = 0; ni < 2; ++ni) {
            int rbase = wm * 64 + mi * 16 + kg * 4;
            int ccol  = wn * 32 + ni * 16 + fr;
            #pragma unroll
            for (int rr = 0; rr < 4; ++rr)
                atomicAdd(&outp[(size_t)(rbase + rr) * KD + ccol], acc[mi][ni][rr]);
        }
}

// ---------------- K4: register-resident Gauss-Jordan inversion (SPD, no pivoting).
__global__ __launch_bounds__(512, 2) void invert_kernel(
    const float* __restrict__ AA, float* __restrict__ Hout)
{
    const int b = blockIdx.x, which = blockIdx.y;
    const float* src = AA + ((size_t)which * BB + b) * KD * KD;
    float* dst = Hout + ((size_t)which * BB + b) * KD * KD;

    __shared__ float rowbuf[2][KD];
    __shared__ float colbuf[2][KD];

    const int tid = threadIdx.x;
    const int rb = tid >> 5;
    const int cg = tid & 31;

    f32x4 Areg[8];
    #pragma unroll
    for (int r = 0; r < 8; ++r)
        Areg[r] = *(const f32x4*)(src + (size_t)(rb * 8 + r) * KD + cg * 4);

    if (rb == 0) *(f32x4*)&rowbuf[0][cg * 4] = Areg[0];
    if (cg == 0) {
        #pragma unroll
        for (int r = 0; r < 8; ++r) colbuf[0][rb * 8 + r] = Areg[r].x;
    }
    __syncthreads();

    for (int j = 0; j < KD; ++j) {
        const int cur = j & 1, nxt = cur ^ 1;
        const int jrb = j >> 3, jr = j & 7, jcg = j >> 2, jc = j & 3;
        const float pv = 1.0f / rowbuf[cur][j];
        const f32x4 orow = *(const f32x4*)&rowbuf[cur][cg * 4];
        const f32x4 prow = orow * pv;
        const bool mycg = (cg == jcg);
        const bool myrb = (rb == jrb);

        #pragma unroll
        for (int r = 0; r < 8; ++r) {
            const float cm = colbuf[cur][rb * 8 + r];
            const float cmul = -cm * pv;
            const bool piv = myrb && (r == jr);
            f32x4 nv;
            nv.x = piv ? prow.x : fmaf(cmul, orow.x, Areg[r].x);
            nv.y = piv ? prow.y : fmaf(cmul, orow.y, Areg[r].y);
            nv.z = piv ? prow.z : fmaf(cmul, orow.z, Areg[r].z);
            nv.w = piv ? prow.w : fmaf(cmul, orow.w, Areg[r].w);
            if (mycg) {
                const float fixv = piv ? pv : cmul;
                nv.x = (jc == 0) ? fixv : nv.x;
                nv.y = (jc == 1) ? fixv : nv.y;
                nv.z = (jc == 2) ? fixv : nv.z;
                nv.w = (jc == 3) ? fixv : nv.w;
            }
            Areg[r] = nv;
        }

        if (j + 1 < KD) {
            const int njrb = (j + 1) >> 3, njr = (j + 1) & 7;
            const int njcg = (j + 1) >> 2, njc = (j + 1) & 3;
            if (rb == njrb) {
                #pragma unroll
                for (int r = 0; r < 8; ++r)
                    if (r == njr) *(f32x4*)&rowbuf[nxt][cg * 4] = Areg[r];
            }
            if (cg == njcg) {
                #pragma unroll
                for (int r = 0; r < 8; ++r) {
                    const f32x4 a = Areg[r];
                    const float e = (njc == 0) ? a.x : (njc == 1) ? a.y : (njc == 2) ? a.z : a.w;
                    colbuf[nxt][rb * 8 + r] = e;
                }
            }
        }
        __syncthreads();
    }

    #pragma unroll
    for (int r = 0; r < 8; ++r)
        *(f32x4*)(dst + (size_t)(rb * 8 + r) * KD + cg * 4) = Areg[r];
}

// ---------------- K5: Neumann-series solve. (rho ~ 3e-3 -> 4 terms ample)
#define NTERMS 4
__global__ __launch_bounds__(512) void solve_kernel(
    const float* __restrict__ AAba, const float* __restrict__ lm_ab,
    const float* __restrict__ lm_ba, const float* __restrict__ Hmat,
    float* __restrict__ outp)
{
    const int b = blockIdx.x, cg = blockIdx.y, which = blockIdx.z;
    const float* Hm = Hmat + ((size_t)which * BB + b) * KD * KD;
    const float* lm = (which ? lm_ba : lm_ab) + (size_t)b * KD * KD;
    const float* Rs = AAba + (size_t)b * KD * KD;
    float* op = outp + ((size_t)which * BB + b) * KD * KD;
    const int i0 = cg * 32;

    __shared__ float Hs[KD][132];
    __shared__ float Zc[2][32][132];
    __shared__ float lms[32][132];

    const int tid = threadIdx.x;
    const int rq = tid & 31;
    const int cq = tid >> 5;

    #pragma unroll
    for (int u = 0; u < 8; ++u) {
        int idx = tid + u * 512;
        int d = idx >> 5, l4 = idx & 31;
        *(float4*)&Hs[d][l4 * 4] = *(const float4*)(Hm + (size_t)d * KD + l4 * 4);
    }
    #pragma unroll
    for (int u = 0; u < 8; ++u) {
        int idx = tid + u * 512;
        int ic = idx >> 7, l = idx & 127;
        lms[ic][l] = lm[(size_t)(i0 + ic) * KD + l];
    }
    if (which == 0) {
        #pragma unroll
        for (int u = 0; u < 8; ++u) {
            int idx = tid + u * 512;
            int ic = idx >> 7, d = idx & 127;
            Zc[0][ic][d] = Rs[(size_t)(i0 + ic) * KD + d];
        }
    } else {
        #pragma unroll
        for (int u = 0; u < 8; ++u) {
            int idx = tid + u * 512;
            int d = idx >> 5, ic = idx & 31;
            Zc[0][ic][d] = Rs[(size_t)d * KD + i0 + ic];
        }
    }
    __syncthreads();

    float xacc[4][2];
    #pragma unroll
    for (int rr = 0; rr < 4; ++rr) { xacc[rr][0] = 0.f; xacc[rr][1] = 0.f; }
    int cur = 0;
    for (int t = 0; t < NTERMS; ++t) {
        float zr[4][2];
        #pragma unroll
        for (int rr = 0; rr < 4; ++rr) { zr[rr][0] = 0.f; zr[rr][1] = 0.f; }
        #pragma unroll 8
        for (int d4 = 0; d4 < 32; ++d4) {
            float4 hv[4];
            #pragma unroll
            for (int dd = 0; dd < 4; ++dd)
                hv[dd] = *(const float4*)&Hs[d4 * 4 + dd][rq * 4];
            float4 wv[2];
            #pragma unroll
            for (int cc = 0; cc < 2; ++cc)
                wv[cc] = *(const float4*)&Zc[cur][cq * 2 + cc][d4 * 4];
            #pragma unroll
            for (int cc = 0; cc < 2; ++cc) {
                zr[0][cc] += hv[0].x * wv[cc].x + hv[1].x * wv[cc].y + hv[2].x * wv[cc].z + hv[3].x * wv[cc].w;
                zr[1][cc] += hv[0].y * wv[cc].x + hv[1].y * wv[cc].y + hv[2].y * wv[cc].z + hv[3].y * wv[cc].w;
                zr[2][cc] += hv[0].z * wv[cc].x + hv[1].z * wv[cc].y + hv[2].z * wv[cc].z + hv[3].z * wv[cc].w;
                zr[3][cc] += hv[0].w * wv[cc].x + hv[1].w * wv[cc].y + hv[2].w * wv[cc].z + hv[3].w * wv[cc].w;
            }
        }
        const float s = (t & 1) ? -1.f : 1.f;
        #pragma unroll
        for (int rr = 0; rr < 4; ++rr) {
            xacc[rr][0] += s * zr[rr][0];
            xacc[rr][1] += s * zr[rr][1];
        }
        if (t + 1 < NTERMS) {
            #pragma unroll
            for (int cc = 0; cc < 2; ++cc) {
                float4 lmv = *(const float4*)&lms[cq * 2 + cc][rq * 4];
                float4 w;
                w.x = lmv.x * zr[0][cc];
                w.y = lmv.y * zr[1][cc];
                w.z = lmv.z * zr[2][cc];
                w.w = lmv.w * zr[3][cc];
                *(float4*)&Zc[cur ^ 1][cq * 2 + cc][rq * 4] = w;
            }
            __syncthreads();
            cur ^= 1;
        }
    }
    #pragma unroll
    for (int cc = 0; cc < 2; ++cc) {
        float4 o;
        o.x = xacc[0][cc]; o.y = xacc[1][cc]; o.z = xacc[2][cc]; o.w = xacc[3][cc];
        *(float4*)(op + (size_t)(i0 + cq * 2 + cc) * KD + rq * 4) = o;
    }
}

extern "C" void kernel_launch(void* const* d_in, const int* in_sizes, int n_in,
                              void* d_out, int out_size, void* d_ws, size_t ws_size,
                              hipStream_t stream) {
    (void)in_sizes; (void)n_in; (void)out_size; (void)ws_size;
    const float* evals_a = (const float*)d_in[0];
    const float* pinv_a  = (const float*)d_in[1];
    const float* descr_a = (const float*)d_in[2];
    const float* evals_b = (const float*)d_in[3];
    const float* pinv_b  = (const float*)d_in[4];
    const float* descr_b = (const float*)d_in[5];
    float* out = (float*)d_out;
    float* ws = (float*)d_ws;

    const size_t SD = (size_t)BB * KD * DD;   // 524288
    const size_t MM = (size_t)BB * KD * KD;   // 262144
    float* sd_a  = ws;
    float* sd_b  = sd_a + SD;
    float* AA    = sd_b + SD;        // 3*MM: [0]=AA_aa [1]=AA_bb [2]=AA_ba
    float* lm_ab = AA + 3 * MM;
    float* lm_ba = lm_ab + MM;
    float* Hm    = lm_ba + MM;       // 2*MM

    // zero sd (proj atomics) and AA (gram atomics)
    hipMemsetAsync(sd_a, 0, (2 * SD + 3 * MM) * sizeof(float), stream);
    proj_kernel<<<dim3(BB, 2, NSL), 1024, 0, stream>>>(pinv_a, descr_a, pinv_b, descr_b, sd_a, sd_b);
    mask_kernel<<<dim3(BB), 256, 0, stream>>>(evals_a, evals_b, lm_ab, lm_ba);
    gram_kernel<<<dim3(BB, 3, 4), 512, 0, stream>>>(sd_a, sd_b, AA);
    invert_kernel<<<dim3(BB, 2), 512, 0, stream>>>(AA, Hm);
    solve_kernel<<<dim3(BB, 4, 2), 512, 0, stream>>>(AA + 2 * MM, lm_ab, lm_ba, Hm, out);
}

// Round 13
// 280.108 us; speedup vs baseline: 1.0586x; 1.0586x over previous
//
#include <hip/hip_runtime.h>

#define BB 16
#define KD 128
#define ND 8000
#define DD 256
#define LMB 1000.0f

typedef __attribute__((ext_vector_type(8))) short bf16x8;
typedef __attribute__((ext_vector_type(4))) short bf16x4;
typedef __attribute__((ext_vector_type(4))) float f32x4;
typedef unsigned short ushort_t;

// exact split: x = hi + lo (hi = truncate-to-bf16, lo = truncate(x - hi))
__device__ __forceinline__ void split_bf16(float x, ushort_t& h, ushort_t& l) {
    unsigned int bi = __float_as_uint(x);
    h = (ushort_t)(bi >> 16);
    float lo = x - __uint_as_float(bi & 0xFFFF0000u);
    l = (ushort_t)(__float_as_uint(lo) >> 16);
}

// RNE split for gram (small data, per-element)
__device__ __forceinline__ void split_bf16_rne(float x, ushort_t& h, ushort_t& l) {
    unsigned int bi = __float_as_uint(x);
    h = (ushort_t)(bi >> 16);
    float lo = x - __uint_as_float(bi & 0xFFFF0000u);
    unsigned int lb = __float_as_uint(lo);
    lb = lb + 0x7FFFu + ((lb >> 16) & 1u);
    l = (ushort_t)(lb >> 16);
}

// two f32x4 (k=0..3, k=4..7) -> bf16 hi/lo fragments
__device__ __forceinline__ void cvt8(f32x4 a, f32x4 b, bf16x8& h, bf16x8& l) {
    #pragma unroll
    for (int j = 0; j < 4; ++j) {
        ushort_t hh, ll;
        split_bf16(a[j], hh, ll); h[j] = (short)hh; l[j] = (short)ll;
        split_bf16(b[j], hh, ll); h[4 + j] = (short)hh; l[4 + j] = (short)ll;
    }
}

// async global->LDS, 16B per lane, lds dest = uniform base + lane*16
__device__ __forceinline__ void gll16(const float* g, float* l) {
    __builtin_amdgcn_global_load_lds(
        (const __attribute__((address_space(1))) void*)g,
        (__attribute__((address_space(3))) void*)l, 16, 0, 0);
}

// ---------------- K1: projection  sd[b][k][d] = sum_n pinv[b][k][n]*descr[b][d][n]
// DEPTH-3 pipeline: 3 x 48KB fp32 staging buffers, chunks t,t+1,t+2 in flight
// (96KB/CU outstanding during compute, 9 loads/wave), counted vmcnt(6) waits
// only the OLDEST chunk (T4 with depth>1 -- the one axis R6..R12 never varied;
// all 1-deep variants plateaued at ~157us = queuing-latency-bound delivery).
// Conversion in fragment path (R12 proved its VALU is fully hidden), A-hoist,
// 8-slot XOR swizzle both sides. grid (16 b, 2 which, 8 slices), 1024 thr =
// 16 waves (4m x 4n), wave tile 32(k) x 64(d), chunks c = s + 8t over [0,250).
#define ROWS 384      // KD + DD
#define CHF 32        // chunk width in floats (K=32)
#define NSL 8
#define SBUF_FL 12288 // ROWS*CHF
#define DEPTH 3

__global__ __attribute__((amdgpu_flat_work_group_size(1024, 1024)))
void proj_kernel(
    const float* __restrict__ pinv_a, const float* __restrict__ descr_a,
    const float* __restrict__ pinv_b, const float* __restrict__ descr_b,
    float* __restrict__ sd_a, float* __restrict__ sd_b)
{
    const int b = blockIdx.x, which = blockIdx.y, s = blockIdx.z;
    const float* P  = (which ? pinv_b  : pinv_a)  + (size_t)b * KD * ND;
    const float* Dm = (which ? descr_b : descr_a) + (size_t)b * DD * ND;
    float* outp = (which ? sd_b : sd_a) + (size_t)b * KD * DD;

    __shared__ float Sbuf[DEPTH][SBUF_FL];

    const int tid = threadIdx.x;
    const int lane = tid & 63;
    const int wid = tid >> 6;                 // 0..15
    const int wm = wid >> 2, wn = wid & 3;    // wave tile: rows wm*32, cols wn*64
    const int fr = lane & 15;
    const int kg = lane >> 4;
    const int NC = (s < 2) ? 32 : 31;         // chunks c = s + 8*t, c in [0,250)

    // staging plan: 48 wave-instrs of 1KB; instr I = wid*3+u covers rows [I*8, I*8+8)
    // lane: row = I*8 + (lane>>3), slot = lane&7; source col-group c4 = slot ^ (row&7)
    const float* gp[3];
    int lof[3];
    #pragma unroll
    for (int u = 0; u < 3; ++u) {
        int I = wid * 3 + u;
        int r = I * 8 + (lane >> 3);
        int c4 = (lane & 7) ^ (r & 7);
        const float* rowp = (r < KD) ? (P + (size_t)r * ND) : (Dm + (size_t)(r - KD) * ND);
        gp[u] = rowp + c4 * 4;
        lof[u] = I * 256;
    }

    f32x4 acc[2][4];
    #pragma unroll
    for (int i = 0; i < 2; ++i)
        #pragma unroll
        for (int j = 0; j < 4; ++j) acc[i][j] = (f32x4){0.f, 0.f, 0.f, 0.f};

    // prologue: stage chunks 0 and 1
    #pragma unroll
    for (int u = 0; u < 3; ++u) gll16(gp[u] + s * CHF, &Sbuf[0][lof[u]]);
    #pragma unroll
    for (int u = 0; u < 3; ++u) gll16(gp[u] + (s + NSL) * CHF, &Sbuf[1][lof[u]]);

    for (int t = 0; t < NC; ++t) {
        if (t + 2 < NC) {
            const int noff = (s + NSL * (t + 2)) * CHF;
            float* dst = &Sbuf[(t + 2) % DEPTH][0];
            #pragma unroll
            for (int u = 0; u < 3; ++u) gll16(gp[u] + noff, dst + lof[u]);
            __builtin_amdgcn_sched_barrier(0);
            asm volatile("s_waitcnt vmcnt(6)" ::: "memory");   // oldest chunk only
        } else if (t + 1 < NC) {
            __builtin_amdgcn_sched_barrier(0);
            asm volatile("s_waitcnt vmcnt(3)" ::: "memory");
        } else {
            __builtin_amdgcn_sched_barrier(0);
            asm volatile("s_waitcnt vmcnt(0)" ::: "memory");
        }
        __builtin_amdgcn_sched_barrier(0);
        __builtin_amdgcn_s_barrier();                          // chunk t ready
        __builtin_amdgcn_sched_barrier(0);

        const float* base = &Sbuf[t % DEPTH][0];

        // A fragments: convert once per chunk (hoisted)
        bf16x8 Ah[2], Al[2];
        #pragma unroll
        for (int mi = 0; mi < 2; ++mi) {
            const int rA = wm * 32 + mi * 16 + fr;
            const int ra7 = rA & 7;
            f32x4 a0 = *(const f32x4*)(base + rA * CHF + (((2 * kg)     ^ ra7) << 2));
            f32x4 a1 = *(const f32x4*)(base + rA * CHF + (((2 * kg + 1) ^ ra7) << 2));
            cvt8(a0, a1, Ah[mi], Al[mi]);
        }
        #pragma unroll
        for (int ni = 0; ni < 4; ++ni) {
            const int rB = KD + wn * 64 + ni * 16 + fr;
            const int rb7 = rB & 7;
            f32x4 b0 = *(const f32x4*)(base + rB * CHF + (((2 * kg)     ^ rb7) << 2));
            f32x4 b1 = *(const f32x4*)(base + rB * CHF + (((2 * kg + 1) ^ rb7) << 2));
            bf16x8 Bh, Bl;
            cvt8(b0, b1, Bh, Bl);
            #pragma unroll
            for (int mi = 0; mi < 2; ++mi) {
                acc[mi][ni] = __builtin_amdgcn_mfma_f32_16x16x32_bf16(Ah[mi], Bh, acc[mi][ni], 0, 0, 0);
                acc[mi][ni] = __builtin_amdgcn_mfma_f32_16x16x32_bf16(Ah[mi], Bl, acc[mi][ni], 0, 0, 0);
                acc[mi][ni] = __builtin_amdgcn_mfma_f32_16x16x32_bf16(Al[mi], Bh, acc[mi][ni], 0, 0, 0);
            }
        }
        __builtin_amdgcn_sched_barrier(0);
        __builtin_amdgcn_s_barrier();       // reads done before buf reuse
    }

    // epilogue: C/D layout col=lane&15, row=(lane>>4)*4+reg (m89)
    #pragma unroll
    for (int mi = 0; mi < 2; ++mi)
        #pragma unroll
        for (int ni = 0; ni < 4; ++ni) {
            int rbase = wm * 32 + mi * 16 + kg * 4;
            int ccol  = wn * 64 + ni * 16 + fr;
            #pragma unroll
            for (int r = 0; r < 4; ++r)
                atomicAdd(&outp[(size_t)(rbase + r) * DD + ccol], acc[mi][ni][r]);
        }
}

// ---------------- K2: masks (lambda folded in)
__global__ __launch_bounds__(256) void mask_kernel(
    const float* __restrict__ ea_g, const float* __restrict__ eb_g,
    float* __restrict__ lm_ab, float* __restrict__ lm_ba)
{
    const int b = blockIdx.x, tid = threadIdx.x;
    __shared__ float ta[KD], ua[KD], tb[KD], ub[KD];
    __shared__ float red[256];
    float e = (tid < KD) ? ea_g[b * KD + tid] : eb_g[b * KD + (tid - KD)];
    red[tid] = e;
    __syncthreads();
    for (int s = 128; s > 0; s >>= 1) {
        if (tid < s) red[tid] = fmaxf(red[tid], red[tid + s]);
        __syncthreads();
    }
    float is = 1.0f / red[0];
    float g = e * is;
    float den = 1.0f / (g * g + 1.0f);
    if (tid < KD) { ta[tid] = g * den; ua[tid] = den; }
    else          { tb[tid - KD] = g * den; ub[tid - KD] = den; }
    __syncthreads();
    for (int idx = tid; idx < KD * KD; idx += 256) {
        int i = idx >> 7, kc = idx & 127;
        float re = tb[i] - ta[kc], im = ub[i] - ua[kc];
        lm_ab[(size_t)b * KD * KD + idx] = LMB * (re * re + im * im);
        float re2 = ta[i] - tb[kc], im2 = ua[i] - ub[kc];
        lm_ba[(size_t)b * KD * KD + idx] = LMB * (re2 * re2 + im2 * im2);
    }
}

// ---------------- K3: Grams via split-bf16 MFMA, d-split for parallelism.
#define GSTR 68
__global__ __launch_bounds__(512, 2) void gram_kernel(
    const float* __restrict__ sd_a, const float* __restrict__ sd_b,
    float* __restrict__ AA)
{
    const int b = blockIdx.x, m = blockIdx.y, dchunk = blockIdx.z;
    const float* X = (m == 0) ? sd_a : sd_b;
    const float* Y = (m == 2) ? sd_a : X;
    X += (size_t)b * KD * DD;
    Y += (size_t)b * KD * DD;
    float* outp = AA + ((size_t)m * BB + b) * KD * KD;
    const int d0 = dchunk * 64;

    __shared__ ushort_t Xh[KD][GSTR], Xl[KD][GSTR];
    __shared__ ushort_t Yh[KD][GSTR], Yl[KD][GSTR];

    const int tid = threadIdx.x;
    const int lane = tid & 63;
    const int wid = tid >> 6;
    const int wm = wid >> 2, wn = wid & 3;
    const int fr = lane & 15;
    const int kg = lane >> 4;

    f32x4 acc[4][2];
    #pragma unroll
    for (int i = 0; i < 4; ++i)
        #pragma unroll
        for (int j = 0; j < 2; ++j) acc[i][j] = (f32x4){0.f, 0.f, 0.f, 0.f};

    #pragma unroll
    for (int u = 0; u < 8; ++u) {
        int idx = tid + (u & 3) * 512;
        int r = idx >> 4, c4 = idx & 15;
        const float* src = (u < 4) ? X : Y;
        float4 v = *(const float4*)(src + (size_t)r * DD + d0 + c4 * 4);
        float xs[4] = {v.x, v.y, v.z, v.w};
        bf16x4 hv, lv;
        #pragma unroll
        for (int q = 0; q < 4; ++q) {
            ushort_t hh, ll;
            split_bf16_rne(xs[q], hh, ll);
            hv[q] = (short)hh; lv[q] = (short)ll;
        }
        if (u < 4) {
            *(bf16x4*)&Xh[r][c4 * 4] = hv;
            *(bf16x4*)&Xl[r][c4 * 4] = lv;
        } else {
            *(bf16x4*)&Yh[r][c4 * 4] = hv;
            *(bf16x4*)&Yl[r][c4 * 4] = lv;
        }
    }
    __syncthreads();

    #pragma unroll
    for (int kk = 0; kk < 2; ++kk) {
        const int co = kk * 32 + kg * 8;
        bf16x8 Ah[4], Al[4];
        #pragma unroll
        for (int mi = 0; mi < 4; ++mi) {
            int r = wm * 64 + mi * 16 + fr;
            Ah[mi] = *(const bf16x8*)&Xh[r][co];
            Al[mi] = *(const bf16x8*)&Xl[r][co];
        }
        #pragma unroll
        for (int ni = 0; ni < 2; ++ni) {
            int c = wn * 32 + ni * 16 + fr;
            bf16x8 Bh = *(const bf16x8*)&Yh[c][co];
            bf16x8 Bl = *(const bf16x8*)&Yl[c][co];
            #pragma unroll
            for (int mi = 0; mi < 4; ++mi) {
                acc[mi][ni] = __builtin_amdgcn_mfma_f32_16x16x32_bf16(Ah[mi], Bh, acc[mi][ni], 0, 0, 0);
                acc[mi][ni] = __builtin_amdgcn_mfma_f32_16x16x32_bf16(Ah[mi], Bl, acc[mi][ni], 0, 0, 0);
                acc[mi][ni] = __builtin_amdgcn_mfma_f32_16x16x32_bf16(Al[mi], Bh, acc[mi][ni], 0, 0, 0);
            }
        }
    }

    #pragma unroll
    for (int mi = 0; mi < 4; ++mi)
        #pragma unroll
        for (int ni = 0; ni < 2; ++ni) {
            int rbase = wm * 64 + mi * 16 + kg * 4;
            int ccol  = wn * 32 + ni * 16 + fr;
            #pragma unroll
            for (int rr = 0; rr < 4; ++rr)
                atomicAdd(&outp[(size_t)(rbase + rr) * KD + ccol], acc[mi][ni][rr]);
        }
}

// ---------------- K4: register-resident Gauss-Jordan inversion (SPD, no pivoting).
__global__ __launch_bounds__(512, 2) void invert_kernel(
    const float* __restrict__ AA, float* __restrict__ Hout)
{
    const int b = blockIdx.x, which = blockIdx.y;
    const float* src = AA + ((size_t)which * BB + b) * KD * KD;
    float* dst = Hout + ((size_t)which * BB + b) * KD * KD;

    __shared__ float rowbuf[2][KD];
    __shared__ float colbuf[2][KD];

    const int tid = threadIdx.x;
    const int rb = tid >> 5;
    const int cg = tid & 31;

    f32x4 Areg[8];
    #pragma unroll
    for (int r = 0; r < 8; ++r)
        Areg[r] = *(const f32x4*)(src + (size_t)(rb * 8 + r) * KD + cg * 4);

    if (rb == 0) *(f32x4*)&rowbuf[0][cg * 4] = Areg[0];
    if (cg == 0) {
        #pragma unroll
        for (int r = 0; r < 8; ++r) colbuf[0][rb * 8 + r] = Areg[r].x;
    }
    __syncthreads();

    for (int j = 0; j < KD; ++j) {
        const int cur = j & 1, nxt = cur ^ 1;
        const int jrb = j >> 3, jr = j & 7, jcg = j >> 2, jc = j & 3;
        const float pv = 1.0f / rowbuf[cur][j];
        const f32x4 orow = *(const f32x4*)&rowbuf[cur][cg * 4];
        const f32x4 prow = orow * pv;
        const bool mycg = (cg == jcg);
        const bool myrb = (rb == jrb);

        #pragma unroll
        for (int r = 0; r < 8; ++r) {
            const float cm = colbuf[cur][rb * 8 + r];
            const float cmul = -cm * pv;
            const bool piv = myrb && (r == jr);
            f32x4 nv;
            nv.x = piv ? prow.x : fmaf(cmul, orow.x, Areg[r].x);
            nv.y = piv ? prow.y : fmaf(cmul, orow.y, Areg[r].y);
            nv.z = piv ? prow.z : fmaf(cmul, orow.z, Areg[r].z);
            nv.w = piv ? prow.w : fmaf(cmul, orow.w, Areg[r].w);
            if (mycg) {
                const float fixv = piv ? pv : cmul;
                nv.x = (jc == 0) ? fixv : nv.x;
                nv.y = (jc == 1) ? fixv : nv.y;
                nv.z = (jc == 2) ? fixv : nv.z;
                nv.w = (jc == 3) ? fixv : nv.w;
            }
            Areg[r] = nv;
        }

        if (j + 1 < KD) {
            const int njrb = (j + 1) >> 3, njr = (j + 1) & 7;
            const int njcg = (j + 1) >> 2, njc = (j + 1) & 3;
            if (rb == njrb) {
                #pragma unroll
                for (int r = 0; r < 8; ++r)
                    if (r == njr) *(f32x4*)&rowbuf[nxt][cg * 4] = Areg[r];
            }
            if (cg == njcg) {
                #pragma unroll
                for (int r = 0; r < 8; ++r) {
                    const f32x4 a = Areg[r];
                    const float e = (njc == 0) ? a.x : (njc == 1) ? a.y : (njc == 2) ? a.z : a.w;
                    colbuf[nxt][rb * 8 + r] = e;
                }
            }
        }
        __syncthreads();
    }

    #pragma unroll
    for (int r = 0; r < 8; ++r)
        *(f32x4*)(dst + (size_t)(rb * 8 + r) * KD + cg * 4) = Areg[r];
}

// ---------------- K5: Neumann-series solve. (rho ~ 3e-3 -> 4 terms ample)
#define NTERMS 4
__global__ __launch_bounds__(512) void solve_kernel(
    const float* __restrict__ AAba, const float* __restrict__ lm_ab,
    const float* __restrict__ lm_ba, const float* __restrict__ Hmat,
    float* __restrict__ outp)
{
    const int b = blockIdx.x, cg = blockIdx.y, which = blockIdx.z;
    const float* Hm = Hmat + ((size_t)which * BB + b) * KD * KD;
    const float* lm = (which ? lm_ba : lm_ab) + (size_t)b * KD * KD;
    const float* Rs = AAba + (size_t)b * KD * KD;
    float* op = outp + ((size_t)which * BB + b) * KD * KD;
    const int i0 = cg * 32;

    __shared__ float Hs[KD][132];
    __shared__ float Zc[2][32][132];
    __shared__ float lms[32][132];

    const int tid = threadIdx.x;
    const int rq = tid & 31;
    const int cq = tid >> 5;

    #pragma unroll
    for (int u = 0; u < 8; ++u) {
        int idx = tid + u * 512;
        int d = idx >> 5, l4 = idx & 31;
        *(float4*)&Hs[d][l4 * 4] = *(const float4*)(Hm + (size_t)d * KD + l4 * 4);
    }
    #pragma unroll
    for (int u = 0; u < 8; ++u) {
        int idx = tid + u * 512;
        int ic = idx >> 7, l = idx & 127;
        lms[ic][l] = lm[(size_t)(i0 + ic) * KD + l];
    }
    if (which == 0) {
        #pragma unroll
        for (int u = 0; u < 8; ++u) {
            int idx = tid + u * 512;
            int ic = idx >> 7, d = idx & 127;
            Zc[0][ic][d] = Rs[(size_t)(i0 + ic) * KD + d];
        }
    } else {
        #pragma unroll
        for (int u = 0; u < 8; ++u) {
            int idx = tid + u * 512;
            int d = idx >> 5, ic = idx & 31;
            Zc[0][ic][d] = Rs[(size_t)d * KD + i0 + ic];
        }
    }
    __syncthreads();

    float xacc[4][2];
    #pragma unroll
    for (int rr = 0; rr < 4; ++rr) { xacc[rr][0] = 0.f; xacc[rr][1] = 0.f; }
    int cur = 0;
    for (int t = 0; t < NTERMS; ++t) {
        float zr[4][2];
        #pragma unroll
        for (int rr = 0; rr < 4; ++rr) { zr[rr][0] = 0.f; zr[rr][1] = 0.f; }
        #pragma unroll 8
        for (int d4 = 0; d4 < 32; ++d4) {
            float4 hv[4];
            #pragma unroll
            for (int dd = 0; dd < 4; ++dd)
                hv[dd] = *(const float4*)&Hs[d4 * 4 + dd][rq * 4];
            float4 wv[2];
            #pragma unroll
            for (int cc = 0; cc < 2; ++cc)
                wv[cc] = *(const float4*)&Zc[cur][cq * 2 + cc][d4 * 4];
            #pragma unroll
            for (int cc = 0; cc < 2; ++cc) {
                zr[0][cc] += hv[0].x * wv[cc].x + hv[1].x * wv[cc].y + hv[2].x * wv[cc].z + hv[3].x * wv[cc].w;
                zr[1][cc] += hv[0].y * wv[cc].x + hv[1].y * wv[cc].y + hv[2].y * wv[cc].z + hv[3].y * wv[cc].w;
                zr[2][cc] += hv[0].z * wv[cc].x + hv[1].z * wv[cc].y + hv[2].z * wv[cc].z + hv[3].z * wv[cc].w;
                zr[3][cc] += hv[0].w * wv[cc].x + hv[1].w * wv[cc].y + hv[2].w * wv[cc].z + hv[3].w * wv[cc].w;
            }
        }
        const float s = (t & 1) ? -1.f : 1.f;
        #pragma unroll
        for (int rr = 0; rr < 4; ++rr) {
            xacc[rr][0] += s * zr[rr][0];
            xacc[rr][1] += s * zr[rr][1];
        }
        if (t + 1 < NTERMS) {
            #pragma unroll
            for (int cc = 0; cc < 2; ++cc) {
                float4 lmv = *(const float4*)&lms[cq * 2 + cc][rq * 4];
                float4 w;
                w.x = lmv.x * zr[0][cc];
                w.y = lmv.y * zr[1][cc];
                w.z = lmv.z * zr[2][cc];
                w.w = lmv.w * zr[3][cc];
                *(float4*)&Zc[cur ^ 1][cq * 2 + cc][rq * 4] = w;
            }
            __syncthreads();
            cur ^= 1;
        }
    }
    #pragma unroll
    for (int cc = 0; cc < 2; ++cc) {
        float4 o;
        o.x = xacc[0][cc]; o.y = xacc[1][cc]; o.z = xacc[2][cc]; o.w = xacc[3][cc];
        *(float4*)(op + (size_t)(i0 + cq * 2 + cc) * KD + rq * 4) = o;
    }
}

extern "C" void kernel_launch(void* const* d_in, const int* in_sizes, int n_in,
                              void* d_out, int out_size, void* d_ws, size_t ws_size,
                              hipStream_t stream) {
    (void)in_sizes; (void)n_in; (void)out_size; (void)ws_size;
    const float* evals_a = (const float*)d_in[0];
    const float* pinv_a  = (const float*)d_in[1];
    const float* descr_a = (const float*)d_in[2];
    const float* evals_b = (const float*)d_in[3];
    const float* pinv_b  = (const float*)d_in[4];
    const float* descr_b = (const float*)d_in[5];
    float* out = (float*)d_out;
    float* ws = (float*)d_ws;

    const size_t SD = (size_t)BB * KD * DD;   // 524288
    const size_t MM = (size_t)BB * KD * KD;   // 262144
    float* sd_a  = ws;
    float* sd_b  = sd_a + SD;
    float* AA    = sd_b + SD;        // 3*MM: [0]=AA_aa [1]=AA_bb [2]=AA_ba
    float* lm_ab = AA + 3 * MM;
    float* lm_ba = lm_ab + MM;
    float* Hm    = lm_ba + MM;       // 2*MM

    // zero sd (proj atomics) and AA (gram atomics)
    hipMemsetAsync(sd_a, 0, (2 * SD + 3 * MM) * sizeof(float), stream);
    proj_kernel<<<dim3(BB, 2, NSL), 1024, 0, stream>>>(pinv_a, descr_a, pinv_b, descr_b, sd_a, sd_b);
    mask_kernel<<<dim3(BB), 256, 0, stream>>>(evals_a, evals_b, lm_ab, lm_ba);
    gram_kernel<<<dim3(BB, 3, 4), 512, 0, stream>>>(sd_a, sd_b, AA);
    invert_kernel<<<dim3(BB, 2), 512, 0, stream>>>(AA, Hm);
    solve_kernel<<<dim3(BB, 4, 2), 512, 0, stream>>>(AA + 2 * MM, lm_ab, lm_ba, Hm, out);
}

// Round 14
// 260.153 us; speedup vs baseline: 1.1398x; 1.0767x over previous
//
#include <hip/hip_runtime.h>

#define BB 16
#define KD 128
#define ND 8000
#define DD 256
#define LMB 1000.0f

typedef __attribute__((ext_vector_type(8))) short bf16x8;
typedef __attribute__((ext_vector_type(4))) short bf16x4;
typedef __attribute__((ext_vector_type(4))) float f32x4;
typedef unsigned short ushort_t;

// exact split: x = hi + lo (hi = truncate-to-bf16, lo = truncate(x - hi))
__device__ __forceinline__ void split_bf16(float x, ushort_t& h, ushort_t& l) {
    unsigned int bi = __float_as_uint(x);
    h = (ushort_t)(bi >> 16);
    float lo = x - __uint_as_float(bi & 0xFFFF0000u);
    l = (ushort_t)(__float_as_uint(lo) >> 16);
}

// RNE split for gram (small data, per-element)
__device__ __forceinline__ void split_bf16_rne(float x, ushort_t& h, ushort_t& l) {
    unsigned int bi = __float_as_uint(x);
    h = (ushort_t)(bi >> 16);
    float lo = x - __uint_as_float(bi & 0xFFFF0000u);
    unsigned int lb = __float_as_uint(lo);
    lb = lb + 0x7FFFu + ((lb >> 16) & 1u);
    l = (ushort_t)(lb >> 16);
}

// two f32x4 (k=0..3, k=4..7) -> bf16 hi/lo fragments
__device__ __forceinline__ void cvt8(f32x4 a, f32x4 b, bf16x8& h, bf16x8& l) {
    #pragma unroll
    for (int j = 0; j < 4; ++j) {
        ushort_t hh, ll;
        split_bf16(a[j], hh, ll); h[j] = (short)hh; l[j] = (short)ll;
        split_bf16(b[j], hh, ll); h[4 + j] = (short)hh; l[4 + j] = (short)ll;
    }
}

// async global->LDS, 16B per lane, lds dest = uniform base + lane*16
__device__ __forceinline__ void gll16(const float* g, float* l) {
    __builtin_amdgcn_global_load_lds(
        (const __attribute__((address_space(1))) void*)g,
        (__attribute__((address_space(3))) void*)l, 16, 0, 0);
}

// ---------------- K1: projection (frozen at R13-best: depth-3 gll pipeline)
#define ROWS 384
#define CHF 32
#define NSL 8
#define SBUF_FL 12288
#define DEPTH 3

__global__ __attribute__((amdgpu_flat_work_group_size(1024, 1024)))
void proj_kernel(
    const float* __restrict__ pinv_a, const float* __restrict__ descr_a,
    const float* __restrict__ pinv_b, const float* __restrict__ descr_b,
    float* __restrict__ sd_a, float* __restrict__ sd_b)
{
    const int b = blockIdx.x, which = blockIdx.y, s = blockIdx.z;
    const float* P  = (which ? pinv_b  : pinv_a)  + (size_t)b * KD * ND;
    const float* Dm = (which ? descr_b : descr_a) + (size_t)b * DD * ND;
    float* outp = (which ? sd_b : sd_a) + (size_t)b * KD * DD;

    __shared__ float Sbuf[DEPTH][SBUF_FL];

    const int tid = threadIdx.x;
    const int lane = tid & 63;
    const int wid = tid >> 6;
    const int wm = wid >> 2, wn = wid & 3;
    const int fr = lane & 15;
    const int kg = lane >> 4;
    const int NC = (s < 2) ? 32 : 31;

    const float* gp[3];
    int lof[3];
    #pragma unroll
    for (int u = 0; u < 3; ++u) {
        int I = wid * 3 + u;
        int r = I * 8 + (lane >> 3);
        int c4 = (lane & 7) ^ (r & 7);
        const float* rowp = (r < KD) ? (P + (size_t)r * ND) : (Dm + (size_t)(r - KD) * ND);
        gp[u] = rowp + c4 * 4;
        lof[u] = I * 256;
    }

    f32x4 acc[2][4];
    #pragma unroll
    for (int i = 0; i < 2; ++i)
        #pragma unroll
        for (int j = 0; j < 4; ++j) acc[i][j] = (f32x4){0.f, 0.f, 0.f, 0.f};

    #pragma unroll
    for (int u = 0; u < 3; ++u) gll16(gp[u] + s * CHF, &Sbuf[0][lof[u]]);
    #pragma unroll
    for (int u = 0; u < 3; ++u) gll16(gp[u] + (s + NSL) * CHF, &Sbuf[1][lof[u]]);

    for (int t = 0; t < NC; ++t) {
        if (t + 2 < NC) {
            const int noff = (s + NSL * (t + 2)) * CHF;
            float* dst = &Sbuf[(t + 2) % DEPTH][0];
            #pragma unroll
            for (int u = 0; u < 3; ++u) gll16(gp[u] + noff, dst + lof[u]);
            __builtin_amdgcn_sched_barrier(0);
            asm volatile("s_waitcnt vmcnt(6)" ::: "memory");
        } else if (t + 1 < NC) {
            __builtin_amdgcn_sched_barrier(0);
            asm volatile("s_waitcnt vmcnt(3)" ::: "memory");
        } else {
            __builtin_amdgcn_sched_barrier(0);
            asm volatile("s_waitcnt vmcnt(0)" ::: "memory");
        }
        __builtin_amdgcn_sched_barrier(0);
        __builtin_amdgcn_s_barrier();
        __builtin_amdgcn_sched_barrier(0);

        const float* base = &Sbuf[t % DEPTH][0];

        bf16x8 Ah[2], Al[2];
        #pragma unroll
        for (int mi = 0; mi < 2; ++mi) {
            const int rA = wm * 32 + mi * 16 + fr;
            const int ra7 = rA & 7;
            f32x4 a0 = *(const f32x4*)(base + rA * CHF + (((2 * kg)     ^ ra7) << 2));
            f32x4 a1 = *(const f32x4*)(base + rA * CHF + (((2 * kg + 1) ^ ra7) << 2));
            cvt8(a0, a1, Ah[mi], Al[mi]);
        }
        #pragma unroll
        for (int ni = 0; ni < 4; ++ni) {
            const int rB = KD + wn * 64 + ni * 16 + fr;
            const int rb7 = rB & 7;
            f32x4 b0 = *(const f32x4*)(base + rB * CHF + (((2 * kg)     ^ rb7) << 2));
            f32x4 b1 = *(const f32x4*)(base + rB * CHF + (((2 * kg + 1) ^ rb7) << 2));
            bf16x8 Bh, Bl;
            cvt8(b0, b1, Bh, Bl);
            #pragma unroll
            for (int mi = 0; mi < 2; ++mi) {
                acc[mi][ni] = __builtin_amdgcn_mfma_f32_16x16x32_bf16(Ah[mi], Bh, acc[mi][ni], 0, 0, 0);
                acc[mi][ni] = __builtin_amdgcn_mfma_f32_16x16x32_bf16(Ah[mi], Bl, acc[mi][ni], 0, 0, 0);
                acc[mi][ni] = __builtin_amdgcn_mfma_f32_16x16x32_bf16(Al[mi], Bh, acc[mi][ni], 0, 0, 0);
            }
        }
        __builtin_amdgcn_sched_barrier(0);
        __builtin_amdgcn_s_barrier();
    }

    #pragma unroll
    for (int mi = 0; mi < 2; ++mi)
        #pragma unroll
        for (int ni = 0; ni < 4; ++ni) {
            int rbase = wm * 32 + mi * 16 + kg * 4;
            int ccol  = wn * 64 + ni * 16 + fr;
            #pragma unroll
            for (int r = 0; r < 4; ++r)
                atomicAdd(&outp[(size_t)(rbase + r) * DD + ccol], acc[mi][ni][r]);
        }
}

// ---------------- K3: Grams via split-bf16 MFMA (unchanged)
#define GSTR 68
__global__ __launch_bounds__(512, 2) void gram_kernel(
    const float* __restrict__ sd_a, const float* __restrict__ sd_b,
    float* __restrict__ AA)
{
    const int b = blockIdx.x, m = blockIdx.y, dchunk = blockIdx.z;
    const float* X = (m == 0) ? sd_a : sd_b;
    const float* Y = (m == 2) ? sd_a : X;
    X += (size_t)b * KD * DD;
    Y += (size_t)b * KD * DD;
    float* outp = AA + ((size_t)m * BB + b) * KD * KD;
    const int d0 = dchunk * 64;

    __shared__ ushort_t Xh[KD][GSTR], Xl[KD][GSTR];
    __shared__ ushort_t Yh[KD][GSTR], Yl[KD][GSTR];

    const int tid = threadIdx.x;
    const int lane = tid & 63;
    const int wid = tid >> 6;
    const int wm = wid >> 2, wn = wid & 3;
    const int fr = lane & 15;
    const int kg = lane >> 4;

    f32x4 acc[4][2];
    #pragma unroll
    for (int i = 0; i < 4; ++i)
        #pragma unroll
        for (int j = 0; j < 2; ++j) acc[i][j] = (f32x4){0.f, 0.f, 0.f, 0.f};

    #pragma unroll
    for (int u = 0; u < 8; ++u) {
        int idx = tid + (u & 3) * 512;
        int r = idx >> 4, c4 = idx & 15;
        const float* src = (u < 4) ? X : Y;
        float4 v = *(const float4*)(src + (size_t)r * DD + d0 + c4 * 4);
        float xs[4] = {v.x, v.y, v.z, v.w};
        bf16x4 hv, lv;
        #pragma unroll
        for (int q = 0; q < 4; ++q) {
            ushort_t hh, ll;
            split_bf16_rne(xs[q], hh, ll);
            hv[q] = (short)hh; lv[q] = (short)ll;
        }
        if (u < 4) {
            *(bf16x4*)&Xh[r][c4 * 4] = hv;
            *(bf16x4*)&Xl[r][c4 * 4] = lv;
        } else {
            *(bf16x4*)&Yh[r][c4 * 4] = hv;
            *(bf16x4*)&Yl[r][c4 * 4] = lv;
        }
    }
    __syncthreads();

    #pragma unroll
    for (int kk = 0; kk < 2; ++kk) {
        const int co = kk * 32 + kg * 8;
        bf16x8 Ah[4], Al[4];
        #pragma unroll
        for (int mi = 0; mi < 4; ++mi) {
            int r = wm * 64 + mi * 16 + fr;
            Ah[mi] = *(const bf16x8*)&Xh[r][co];
            Al[mi] = *(const bf16x8*)&Xl[r][co];
        }
        #pragma unroll
        for (int ni = 0; ni < 2; ++ni) {
            int c = wn * 32 + ni * 16 + fr;
            bf16x8 Bh = *(const bf16x8*)&Yh[c][co];
            bf16x8 Bl = *(const bf16x8*)&Yl[c][co];
            #pragma unroll
            for (int mi = 0; mi < 4; ++mi) {
                acc[mi][ni] = __builtin_amdgcn_mfma_f32_16x16x32_bf16(Ah[mi], Bh, acc[mi][ni], 0, 0, 0);
                acc[mi][ni] = __builtin_amdgcn_mfma_f32_16x16x32_bf16(Ah[mi], Bl, acc[mi][ni], 0, 0, 0);
                acc[mi][ni] = __builtin_amdgcn_mfma_f32_16x16x32_bf16(Al[mi], Bh, acc[mi][ni], 0, 0, 0);
            }
        }
    }

    #pragma unroll
    for (int mi = 0; mi < 4; ++mi)
        #pragma unroll
        for (int ni = 0; ni < 2; ++ni) {
            int rbase = wm * 64 + mi * 16 + kg * 4;
            int ccol  = wn * 32 + ni * 16 + fr;
            #pragma unroll
            for (int rr = 0; rr < 4; ++rr)
                atomicAdd(&outp[(size_t)(rbase + rr) * KD + ccol], acc[mi][ni][rr]);
        }
}

// ---------------- K4: register-resident Gauss-Jordan inversion (unchanged)
__global__ __launch_bounds__(512, 2) void invert_kernel(
    const float* __restrict__ AA, float* __restrict__ Hout)
{
    const int b = blockIdx.x, which = blockIdx.y;
    const float* src = AA + ((size_t)which * BB + b) * KD * KD;
    float* dst = Hout + ((size_t)which * BB + b) * KD * KD;

    __shared__ float rowbuf[2][KD];
    __shared__ float colbuf[2][KD];

    const int tid = threadIdx.x;
    const int rb = tid >> 5;
    const int cg = tid & 31;

    f32x4 Areg[8];
    #pragma unroll
    for (int r = 0; r < 8; ++r)
        Areg[r] = *(const f32x4*)(src + (size_t)(rb * 8 + r) * KD + cg * 4);

    if (rb == 0) *(f32x4*)&rowbuf[0][cg * 4] = Areg[0];
    if (cg == 0) {
        #pragma unroll
        for (int r = 0; r < 8; ++r) colbuf[0][rb * 8 + r] = Areg[r].x;
    }
    __syncthreads();

    for (int j = 0; j < KD; ++j) {
        const int cur = j & 1, nxt = cur ^ 1;
        const int jrb = j >> 3, jr = j & 7, jcg = j >> 2, jc = j & 3;
        const float pv = 1.0f / rowbuf[cur][j];
        const f32x4 orow = *(const f32x4*)&rowbuf[cur][cg * 4];
        const f32x4 prow = orow * pv;
        const bool mycg = (cg == jcg);
        const bool myrb = (rb == jrb);

        #pragma unroll
        for (int r = 0; r < 8; ++r) {
            const float cm = colbuf[cur][rb * 8 + r];
            const float cmul = -cm * pv;
            const bool piv = myrb && (r == jr);
            f32x4 nv;
            nv.x = piv ? prow.x : fmaf(cmul, orow.x, Areg[r].x);
            nv.y = piv ? prow.y : fmaf(cmul, orow.y, Areg[r].y);
            nv.z = piv ? prow.z : fmaf(cmul, orow.z, Areg[r].z);
            nv.w = piv ? prow.w : fmaf(cmul, orow.w, Areg[r].w);
            if (mycg) {
                const float fixv = piv ? pv : cmul;
                nv.x = (jc == 0) ? fixv : nv.x;
                nv.y = (jc == 1) ? fixv : nv.y;
                nv.z = (jc == 2) ? fixv : nv.z;
                nv.w = (jc == 3) ? fixv : nv.w;
            }
            Areg[r] = nv;
        }

        if (j + 1 < KD) {
            const int njrb = (j + 1) >> 3, njr = (j + 1) & 7;
            const int njcg = (j + 1) >> 2, njc = (j + 1) & 3;
            if (rb == njrb) {
                #pragma unroll
                for (int r = 0; r < 8; ++r)
                    if (r == njr) *(f32x4*)&rowbuf[nxt][cg * 4] = Areg[r];
            }
            if (cg == njcg) {
                #pragma unroll
                for (int r = 0; r < 8; ++r) {
                    const f32x4 a = Areg[r];
                    const float e = (njc == 0) ? a.x : (njc == 1) ? a.y : (njc == 2) ? a.z : a.w;
                    colbuf[nxt][rb * 8 + r] = e;
                }
            }
        }
        __syncthreads();
    }

    #pragma unroll
    for (int r = 0; r < 8; ++r)
        *(f32x4*)(dst + (size_t)(rb * 8 + r) * KD + cg * 4) = Areg[r];
}

// ---------------- K5: MFMA Neumann solve with fused mask.
// Per block (b, cg 0..3, which): 32 output rows i. Z = H*W is a GEMM
// (M=128 l, N=32 i, K=128 d) on split-bf16 H (converted once, stride-136-ushort
// planes -> exactly 2-way bank aliasing = free). Per term: 24 MFMA + 24 b128
// per wave (8x fewer LDS reads than the scalar-FMA version), then elementwise
// w = lmT(.)z + bf16 split in-register, written back as next term's B operand.
// lmT recomputed in-block from evals (mask_kernel deleted).
#define NTERMS 4
#define HSTR 136
__global__ __launch_bounds__(512) void solve_kernel(
    const float* __restrict__ AAba, const float* __restrict__ ea_g,
    const float* __restrict__ eb_g, const float* __restrict__ Hmat,
    float* __restrict__ outp)
{
    const int b = blockIdx.x, cg = blockIdx.y, which = blockIdx.z;
    const float* Hm = Hmat + ((size_t)which * BB + b) * KD * KD;
    const float* Rs = AAba + (size_t)b * KD * KD;
    float* op = outp + ((size_t)which * BB + b) * KD * KD;
    const int i0 = cg * 32;

    __shared__ ushort_t Hh[KD][HSTR], Hl[KD][HSTR];   // 69.6 KB
    __shared__ ushort_t Wh[32][HSTR], Wl[32][HSTR];   // 17.4 KB
    __shared__ float lmT[KD][33];                     // 16.9 KB  [l][i]
    __shared__ float tC[KD], uC[KD], tR[32], uR[32];
    __shared__ float red[256];

    const int tid = threadIdx.x;
    const int lane = tid & 63;
    const int wid = tid >> 6;                 // 0..7
    const int wl = wid & 3, wi = wid >> 2;    // wave tile: l = wl*32.., i = wi*16..
    const int fr = lane & 15;
    const int kg = lane >> 4;

    // --- fused mask: scale = max over BOTH eval sets
    if (tid < 256) {
        float e = (tid < KD) ? ea_g[b * KD + tid] : eb_g[b * KD + (tid - KD)];
        red[tid] = e;
    }
    __syncthreads();
    for (int s = 128; s > 0; s >>= 1) {
        if (tid < s) red[tid] = fmaxf(red[tid], red[tid + s]);
        __syncthreads();
    }
    const float is = 1.0f / red[0];
    const float* Ce = which ? eb_g : ea_g;    // col evals (index l)
    const float* Re = which ? ea_g : eb_g;    // row evals (index i)
    if (tid < KD) {
        float g = Ce[b * KD + tid] * is;
        float den = 1.0f / (g * g + 1.0f);
        tC[tid] = g * den; uC[tid] = den;
    } else if (tid < KD + 32) {
        int i = tid - KD;
        float g = Re[b * KD + i0 + i] * is;
        float den = 1.0f / (g * g + 1.0f);
        tR[i] = g * den; uR[i] = den;
    }
    __syncthreads();
    #pragma unroll
    for (int u = 0; u < 8; ++u) {
        int idx = tid + u * 512;
        int l = idx >> 5, i = idx & 31;
        float re = tR[i] - tC[l], im = uR[i] - uC[l];
        lmT[l][i] = LMB * (re * re + im * im);
    }

    // --- H -> bf16 hi/lo planes (once; H symmetric so [d][l] load == [l][d])
    #pragma unroll
    for (int u = 0; u < 8; ++u) {
        int idx4 = (tid + u * 512) * 4;       // 16384 floats
        int row = idx4 >> 7, col = idx4 & 127;
        f32x4 v = *(const f32x4*)(Hm + (size_t)row * KD + col);
        bf16x4 hv, lv;
        #pragma unroll
        for (int q = 0; q < 4; ++q) {
            ushort_t hh, ll;
            split_bf16(v[q], hh, ll);
            hv[q] = (short)hh; lv[q] = (short)ll;
        }
        *(bf16x4*)&Hh[row][col] = hv;
        *(bf16x4*)&Hl[row][col] = lv;
    }
    // --- W0[i][d] = r_i[d]
    if (which == 0) {
        #pragma unroll
        for (int u = 0; u < 2; ++u) {
            int idx4 = (tid + u * 512) * 4;   // 4096 floats
            int i = idx4 >> 7, d = idx4 & 127;
            f32x4 v = *(const f32x4*)(Rs + (size_t)(i0 + i) * KD + d);
            bf16x4 hv, lv;
            #pragma unroll
            for (int q = 0; q < 4; ++q) {
                ushort_t hh, ll;
                split_bf16(v[q], hh, ll);
                hv[q] = (short)hh; lv[q] = (short)ll;
            }
            *(bf16x4*)&Wh[i][d] = hv;
            *(bf16x4*)&Wl[i][d] = lv;
        }
    } else {
        #pragma unroll
        for (int u = 0; u < 8; ++u) {
            int idx = tid + u * 512;          // 4096
            int i = idx & 31, d = idx >> 5;
            float v = Rs[(size_t)d * KD + i0 + i];
            ushort_t hh, ll;
            split_bf16(v, hh, ll);
            Wh[i][d] = hh; Wl[i][d] = ll;
        }
    }
    __syncthreads();

    f32x4 xacc[2];
    xacc[0] = (f32x4){0.f, 0.f, 0.f, 0.f};
    xacc[1] = (f32x4){0.f, 0.f, 0.f, 0.f};

    for (int t = 0; t < NTERMS; ++t) {
        f32x4 az[2];
        az[0] = (f32x4){0.f, 0.f, 0.f, 0.f};
        az[1] = (f32x4){0.f, 0.f, 0.f, 0.f};
        #pragma unroll
        for (int kk = 0; kk < 4; ++kk) {
            const int co = kk * 32 + kg * 8;
            bf16x8 Bh = *(const bf16x8*)&Wh[wi * 16 + fr][co];
            bf16x8 Bl = *(const bf16x8*)&Wl[wi * 16 + fr][co];
            #pragma unroll
            for (int mi = 0; mi < 2; ++mi) {
                const int rA = wl * 32 + mi * 16 + fr;
                bf16x8 Ah_ = *(const bf16x8*)&Hh[rA][co];
                bf16x8 Al_ = *(const bf16x8*)&Hl[rA][co];
                az[mi] = __builtin_amdgcn_mfma_f32_16x16x32_bf16(Ah_, Bh, az[mi], 0, 0, 0);
                az[mi] = __builtin_amdgcn_mfma_f32_16x16x32_bf16(Ah_, Bl, az[mi], 0, 0, 0);
                az[mi] = __builtin_amdgcn_mfma_f32_16x16x32_bf16(Al_, Bh, az[mi], 0, 0, 0);
            }
        }
        const float sg = (t & 1) ? -1.f : 1.f;
        #pragma unroll
        for (int mi = 0; mi < 2; ++mi) {
            xacc[mi][0] += sg * az[mi][0];
            xacc[mi][1] += sg * az[mi][1];
            xacc[mi][2] += sg * az[mi][2];
            xacc[mi][3] += sg * az[mi][3];
        }
        if (t + 1 < NTERMS) {
            __syncthreads();                  // all W reads done
            const int i = wi * 16 + fr;
            #pragma unroll
            for (int mi = 0; mi < 2; ++mi) {
                const int l0 = wl * 32 + mi * 16 + kg * 4;
                bf16x4 hv, lv;
                #pragma unroll
                for (int r = 0; r < 4; ++r) {
                    float w = lmT[l0 + r][i] * az[mi][r];
                    ushort_t hh, ll;
                    split_bf16(w, hh, ll);
                    hv[r] = (short)hh; lv[r] = (short)ll;
                }
                *(bf16x4*)&Wh[i][l0] = hv;
                *(bf16x4*)&Wl[i][l0] = lv;
            }
            __syncthreads();                  // W' visible
        }
    }

    // epilogue: out[i0+i][l] ; D-frag col=lane&15 (i), row=kg*4+r (l)
    const int i = wi * 16 + fr;
    #pragma unroll
    for (int mi = 0; mi < 2; ++mi) {
        const int l0 = wl * 32 + mi * 16 + kg * 4;
        float4 o;
        o.x = xacc[mi][0]; o.y = xacc[mi][1]; o.z = xacc[mi][2]; o.w = xacc[mi][3];
        *(float4*)(op + (size_t)(i0 + i) * KD + l0) = o;
    }
}

extern "C" void kernel_launch(void* const* d_in, const int* in_sizes, int n_in,
                              void* d_out, int out_size, void* d_ws, size_t ws_size,
                              hipStream_t stream) {
    (void)in_sizes; (void)n_in; (void)out_size; (void)ws_size;
    const float* evals_a = (const float*)d_in[0];
    const float* pinv_a  = (const float*)d_in[1];
    const float* descr_a = (const float*)d_in[2];
    const float* evals_b = (const float*)d_in[3];
    const float* pinv_b  = (const float*)d_in[4];
    const float* descr_b = (const float*)d_in[5];
    float* out = (float*)d_out;
    float* ws = (float*)d_ws;

    const size_t SD = (size_t)BB * KD * DD;   // 524288
    const size_t MM = (size_t)BB * KD * KD;   // 262144
    float* sd_a  = ws;
    float* sd_b  = sd_a + SD;
    float* AA    = sd_b + SD;        // 3*MM: [0]=AA_aa [1]=AA_bb [2]=AA_ba
    float* Hm    = AA + 3 * MM;      // 2*MM

    // zero sd (proj atomics) and AA (gram atomics)
    hipMemsetAsync(sd_a, 0, (2 * SD + 3 * MM) * sizeof(float), stream);
    proj_kernel<<<dim3(BB, 2, NSL), 1024, 0, stream>>>(pinv_a, descr_a, pinv_b, descr_b, sd_a, sd_b);
    gram_kernel<<<dim3(BB, 3, 4), 512, 0, stream>>>(sd_a, sd_b, AA);
    invert_kernel<<<dim3(BB, 2), 512, 0, stream>>>(AA, Hm);
    solve_kernel<<<dim3(BB, 4, 2), 512, 0, stream>>>(AA + 2 * MM, evals_a, evals_b, Hm, out);
}

// Round 15
// 258.049 us; speedup vs baseline: 1.1490x; 1.0082x over previous
//
#include <hip/hip_runtime.h>

#define BB 16
#define KD 128
#define ND 8000
#define DD 256
#define LMB 1000.0f

typedef __attribute__((ext_vector_type(8))) short bf16x8;
typedef __attribute__((ext_vector_type(4))) short bf16x4;
typedef __attribute__((ext_vector_type(4))) float f32x4;
typedef unsigned short ushort_t;

// exact split: x = hi + lo (hi = truncate-to-bf16, lo = truncate(x - hi))
__device__ __forceinline__ void split_bf16(float x, ushort_t& h, ushort_t& l) {
    unsigned int bi = __float_as_uint(x);
    h = (ushort_t)(bi >> 16);
    float lo = x - __uint_as_float(bi & 0xFFFF0000u);
    l = (ushort_t)(__float_as_uint(lo) >> 16);
}

// RNE split for gram (small data, per-element)
__device__ __forceinline__ void split_bf16_rne(float x, ushort_t& h, ushort_t& l) {
    unsigned int bi = __float_as_uint(x);
    h = (ushort_t)(bi >> 16);
    float lo = x - __uint_as_float(bi & 0xFFFF0000u);
    unsigned int lb = __float_as_uint(lo);
    lb = lb + 0x7FFFu + ((lb >> 16) & 1u);
    l = (ushort_t)(lb >> 16);
}

// two f32x4 (k=0..3, k=4..7) -> bf16 hi/lo fragments
__device__ __forceinline__ void cvt8(f32x4 a, f32x4 b, bf16x8& h, bf16x8& l) {
    #pragma unroll
    for (int j = 0; j < 4; ++j) {
        ushort_t hh, ll;
        split_bf16(a[j], hh, ll); h[j] = (short)hh; l[j] = (short)ll;
        split_bf16(b[j], hh, ll); h[4 + j] = (short)hh; l[4 + j] = (short)ll;
    }
}

// async global->LDS, 16B per lane, lds dest = uniform base + lane*16
__device__ __forceinline__ void gll16(const float* g, float* l) {
    __builtin_amdgcn_global_load_lds(
        (const __attribute__((address_space(1))) void*)g,
        (__attribute__((address_space(3))) void*)l, 16, 0, 0);
}

// ---------------- K1: projection (depth-3 gll pipeline, SINGLE barrier/chunk).
// Sync proof: iteration t = [vmcnt(3) -> barrier -> issue gll(t+2) -> compute t].
// Writes to buf (t+2)%3 happen after barrier_t; all reads of that buffer were in
// iteration t-1, before those waves reached barrier_t -> no WAR race. Arrival:
// each wave's vmcnt(3) drains its own chunk-t loads; barrier then guarantees
// every wave's chunk-t loads are done -> cross-wave reads safe.
#define ROWS 384
#define CHF 32
#define NSL 8
#define SBUF_FL 12288
#define DEPTH 3

__global__ __attribute__((amdgpu_flat_work_group_size(1024, 1024)))
void proj_kernel(
    const float* __restrict__ pinv_a, const float* __restrict__ descr_a,
    const float* __restrict__ pinv_b, const float* __restrict__ descr_b,
    float* __restrict__ sd_a, float* __restrict__ sd_b)
{
    const int b = blockIdx.x, which = blockIdx.y, s = blockIdx.z;
    const float* P  = (which ? pinv_b  : pinv_a)  + (size_t)b * KD * ND;
    const float* Dm = (which ? descr_b : descr_a) + (size_t)b * DD * ND;
    float* outp = (which ? sd_b : sd_a) + (size_t)b * KD * DD;

    __shared__ float Sbuf[DEPTH][SBUF_FL];

    const int tid = threadIdx.x;
    const int lane = tid & 63;
    const int wid = tid >> 6;
    const int wm = wid >> 2, wn = wid & 3;
    const int fr = lane & 15;
    const int kg = lane >> 4;
    const int NC = (s < 2) ? 32 : 31;

    const float* gp[3];
    int lof[3];
    #pragma unroll
    for (int u = 0; u < 3; ++u) {
        int I = wid * 3 + u;
        int r = I * 8 + (lane >> 3);
        int c4 = (lane & 7) ^ (r & 7);
        const float* rowp = (r < KD) ? (P + (size_t)r * ND) : (Dm + (size_t)(r - KD) * ND);
        gp[u] = rowp + c4 * 4;
        lof[u] = I * 256;
    }

    f32x4 acc[2][4];
    #pragma unroll
    for (int i = 0; i < 2; ++i)
        #pragma unroll
        for (int j = 0; j < 4; ++j) acc[i][j] = (f32x4){0.f, 0.f, 0.f, 0.f};

    #pragma unroll
    for (int u = 0; u < 3; ++u) gll16(gp[u] + s * CHF, &Sbuf[0][lof[u]]);
    #pragma unroll
    for (int u = 0; u < 3; ++u) gll16(gp[u] + (s + NSL) * CHF, &Sbuf[1][lof[u]]);

    for (int t = 0; t < NC; ++t) {
        if (t + 1 < NC) {
            asm volatile("s_waitcnt vmcnt(3)" ::: "memory");   // my chunk-t loads done
        } else {
            asm volatile("s_waitcnt vmcnt(0)" ::: "memory");
        }
        __builtin_amdgcn_sched_barrier(0);
        __builtin_amdgcn_s_barrier();                          // everyone's chunk t ready
        __builtin_amdgcn_sched_barrier(0);
        if (t + 2 < NC) {
            const int noff = (s + NSL * (t + 2)) * CHF;
            float* dst = &Sbuf[(t + 2) % DEPTH][0];
            #pragma unroll
            for (int u = 0; u < 3; ++u) gll16(gp[u] + noff, dst + lof[u]);
        }
        __builtin_amdgcn_sched_barrier(0);

        const float* base = &Sbuf[t % DEPTH][0];

        bf16x8 Ah[2], Al[2];
        #pragma unroll
        for (int mi = 0; mi < 2; ++mi) {
            const int rA = wm * 32 + mi * 16 + fr;
            const int ra7 = rA & 7;
            f32x4 a0 = *(const f32x4*)(base + rA * CHF + (((2 * kg)     ^ ra7) << 2));
            f32x4 a1 = *(const f32x4*)(base + rA * CHF + (((2 * kg + 1) ^ ra7) << 2));
            cvt8(a0, a1, Ah[mi], Al[mi]);
        }
        #pragma unroll
        for (int ni = 0; ni < 4; ++ni) {
            const int rB = KD + wn * 64 + ni * 16 + fr;
            const int rb7 = rB & 7;
            f32x4 b0 = *(const f32x4*)(base + rB * CHF + (((2 * kg)     ^ rb7) << 2));
            f32x4 b1 = *(const f32x4*)(base + rB * CHF + (((2 * kg + 1) ^ rb7) << 2));
            bf16x8 Bh, Bl;
            cvt8(b0, b1, Bh, Bl);
            #pragma unroll
            for (int mi = 0; mi < 2; ++mi) {
                acc[mi][ni] = __builtin_amdgcn_mfma_f32_16x16x32_bf16(Ah[mi], Bh, acc[mi][ni], 0, 0, 0);
                acc[mi][ni] = __builtin_amdgcn_mfma_f32_16x16x32_bf16(Ah[mi], Bl, acc[mi][ni], 0, 0, 0);
                acc[mi][ni] = __builtin_amdgcn_mfma_f32_16x16x32_bf16(Al[mi], Bh, acc[mi][ni], 0, 0, 0);
            }
        }
        __builtin_amdgcn_sched_barrier(0);
    }

    #pragma unroll
    for (int mi = 0; mi < 2; ++mi)
        #pragma unroll
        for (int ni = 0; ni < 4; ++ni) {
            int rbase = wm * 32 + mi * 16 + kg * 4;
            int ccol  = wn * 64 + ni * 16 + fr;
            #pragma unroll
            for (int r = 0; r < 4; ++r)
                atomicAdd(&outp[(size_t)(rbase + r) * DD + ccol], acc[mi][ni][r]);
        }
}

// ---------------- K3: Grams via split-bf16 MFMA (unchanged)
#define GSTR 68
__global__ __launch_bounds__(512, 2) void gram_kernel(
    const float* __restrict__ sd_a, const float* __restrict__ sd_b,
    float* __restrict__ AA)
{
    const int b = blockIdx.x, m = blockIdx.y, dchunk = blockIdx.z;
    const float* X = (m == 0) ? sd_a : sd_b;
    const float* Y = (m == 2) ? sd_a : X;
    X += (size_t)b * KD * DD;
    Y += (size_t)b * KD * DD;
    float* outp = AA + ((size_t)m * BB + b) * KD * KD;
    const int d0 = dchunk * 64;

    __shared__ ushort_t Xh[KD][GSTR], Xl[KD][GSTR];
    __shared__ ushort_t Yh[KD][GSTR], Yl[KD][GSTR];

    const int tid = threadIdx.x;
    const int lane = tid & 63;
    const int wid = tid >> 6;
    const int wm = wid >> 2, wn = wid & 3;
    const int fr = lane & 15;
    const int kg = lane >> 4;

    f32x4 acc[4][2];
    #pragma unroll
    for (int i = 0; i < 4; ++i)
        #pragma unroll
        for (int j = 0; j < 2; ++j) acc[i][j] = (f32x4){0.f, 0.f, 0.f, 0.f};

    #pragma unroll
    for (int u = 0; u < 8; ++u) {
        int idx = tid + (u & 3) * 512;
        int r = idx >> 4, c4 = idx & 15;
        const float* src = (u < 4) ? X : Y;
        float4 v = *(const float4*)(src + (size_t)r * DD + d0 + c4 * 4);
        float xs[4] = {v.x, v.y, v.z, v.w};
        bf16x4 hv, lv;
        #pragma unroll
        for (int q = 0; q < 4; ++q) {
            ushort_t hh, ll;
            split_bf16_rne(xs[q], hh, ll);
            hv[q] = (short)hh; lv[q] = (short)ll;
        }
        if (u < 4) {
            *(bf16x4*)&Xh[r][c4 * 4] = hv;
            *(bf16x4*)&Xl[r][c4 * 4] = lv;
        } else {
            *(bf16x4*)&Yh[r][c4 * 4] = hv;
            *(bf16x4*)&Yl[r][c4 * 4] = lv;
        }
    }
    __syncthreads();

    #pragma unroll
    for (int kk = 0; kk < 2; ++kk) {
        const int co = kk * 32 + kg * 8;
        bf16x8 Ah[4], Al[4];
        #pragma unroll
        for (int mi = 0; mi < 4; ++mi) {
            int r = wm * 64 + mi * 16 + fr;
            Ah[mi] = *(const bf16x8*)&Xh[r][co];
            Al[mi] = *(const bf16x8*)&Xl[r][co];
        }
        #pragma unroll
        for (int ni = 0; ni < 2; ++ni) {
            int c = wn * 32 + ni * 16 + fr;
            bf16x8 Bh = *(const bf16x8*)&Yh[c][co];
            bf16x8 Bl = *(const bf16x8*)&Yl[c][co];
            #pragma unroll
            for (int mi = 0; mi < 4; ++mi) {
                acc[mi][ni] = __builtin_amdgcn_mfma_f32_16x16x32_bf16(Ah[mi], Bh, acc[mi][ni], 0, 0, 0);
                acc[mi][ni] = __builtin_amdgcn_mfma_f32_16x16x32_bf16(Ah[mi], Bl, acc[mi][ni], 0, 0, 0);
                acc[mi][ni] = __builtin_amdgcn_mfma_f32_16x16x32_bf16(Al[mi], Bh, acc[mi][ni], 0, 0, 0);
            }
        }
    }

    #pragma unroll
    for (int mi = 0; mi < 4; ++mi)
        #pragma unroll
        for (int ni = 0; ni < 2; ++ni) {
            int rbase = wm * 64 + mi * 16 + kg * 4;
            int ccol  = wn * 32 + ni * 16 + fr;
            #pragma unroll
            for (int rr = 0; rr < 4; ++rr)
                atomicAdd(&outp[(size_t)(rbase + rr) * KD + ccol], acc[mi][ni][rr]);
        }
}

// ---------------- K4: register-resident GJ inversion; emits SPLIT-BF16 H planes
// directly from registers (no fp32 H roundtrip; solve's per-block re-conversion
// deleted). Hbf layout: [which*16+b][plane(hi=0,lo=1)][128][128] ushort.
__global__ __launch_bounds__(512, 2) void invert_kernel(
    const float* __restrict__ AA, ushort_t* __restrict__ Hbf)
{
    const int b = blockIdx.x, which = blockIdx.y;
    const float* src = AA + ((size_t)which * BB + b) * KD * KD;
    ushort_t* dh = Hbf + (size_t)(which * BB + b) * 2 * KD * KD;
    ushort_t* dl = dh + (size_t)KD * KD;

    __shared__ float rowbuf[2][KD];
    __shared__ float colbuf[2][KD];

    const int tid = threadIdx.x;
    const int rb = tid >> 5;
    const int cg = tid & 31;

    f32x4 Areg[8];
    #pragma unroll
    for (int r = 0; r < 8; ++r)
        Areg[r] = *(const f32x4*)(src + (size_t)(rb * 8 + r) * KD + cg * 4);

    if (rb == 0) *(f32x4*)&rowbuf[0][cg * 4] = Areg[0];
    if (cg == 0) {
        #pragma unroll
        for (int r = 0; r < 8; ++r) colbuf[0][rb * 8 + r] = Areg[r].x;
    }
    __syncthreads();

    for (int j = 0; j < KD; ++j) {
        const int cur = j & 1, nxt = cur ^ 1;
        const int jrb = j >> 3, jr = j & 7, jcg = j >> 2, jc = j & 3;
        const float pv = 1.0f / rowbuf[cur][j];
        const f32x4 orow = *(const f32x4*)&rowbuf[cur][cg * 4];
        const f32x4 prow = orow * pv;
        const bool mycg = (cg == jcg);
        const bool myrb = (rb == jrb);

        #pragma unroll
        for (int r = 0; r < 8; ++r) {
            const float cm = colbuf[cur][rb * 8 + r];
            const float cmul = -cm * pv;
            const bool piv = myrb && (r == jr);
            f32x4 nv;
            nv.x = piv ? prow.x : fmaf(cmul, orow.x, Areg[r].x);
            nv.y = piv ? prow.y : fmaf(cmul, orow.y, Areg[r].y);
            nv.z = piv ? prow.z : fmaf(cmul, orow.z, Areg[r].z);
            nv.w = piv ? prow.w : fmaf(cmul, orow.w, Areg[r].w);
            if (mycg) {
                const float fixv = piv ? pv : cmul;
                nv.x = (jc == 0) ? fixv : nv.x;
                nv.y = (jc == 1) ? fixv : nv.y;
                nv.z = (jc == 2) ? fixv : nv.z;
                nv.w = (jc == 3) ? fixv : nv.w;
            }
            Areg[r] = nv;
        }

        if (j + 1 < KD) {
            const int njrb = (j + 1) >> 3, njr = (j + 1) & 7;
            const int njcg = (j + 1) >> 2, njc = (j + 1) & 3;
            if (rb == njrb) {
                #pragma unroll
                for (int r = 0; r < 8; ++r)
                    if (r == njr) *(f32x4*)&rowbuf[nxt][cg * 4] = Areg[r];
            }
            if (cg == njcg) {
                #pragma unroll
                for (int r = 0; r < 8; ++r) {
                    const f32x4 a = Areg[r];
                    const float e = (njc == 0) ? a.x : (njc == 1) ? a.y : (njc == 2) ? a.z : a.w;
                    colbuf[nxt][rb * 8 + r] = e;
                }
            }
        }
        __syncthreads();
    }

    #pragma unroll
    for (int r = 0; r < 8; ++r) {
        bf16x4 hv, lv;
        #pragma unroll
        for (int q = 0; q < 4; ++q) {
            ushort_t hh, ll;
            split_bf16(Areg[r][q], hh, ll);
            hv[q] = (short)hh; lv[q] = (short)ll;
        }
        const size_t off = (size_t)(rb * 8 + r) * KD + cg * 4;
        *(bf16x4*)(dh + off) = hv;
        *(bf16x4*)(dl + off) = lv;
    }
}

// ---------------- K5: MFMA Neumann solve with fused mask; loads PRE-SPLIT H.
#define NTERMS 3
#define HSTR 136
__global__ __launch_bounds__(512) void solve_kernel(
    const float* __restrict__ AAba, const float* __restrict__ ea_g,
    const float* __restrict__ eb_g, const ushort_t* __restrict__ Hbf,
    float* __restrict__ outp)
{
    const int b = blockIdx.x, cg = blockIdx.y, which = blockIdx.z;
    const ushort_t* Hg = Hbf + (size_t)(which * BB + b) * 2 * KD * KD;
    const float* Rs = AAba + (size_t)b * KD * KD;
    float* op = outp + ((size_t)which * BB + b) * KD * KD;
    const int i0 = cg * 32;

    __shared__ ushort_t Hh[KD][HSTR], Hl[KD][HSTR];
    __shared__ ushort_t Wh[32][HSTR], Wl[32][HSTR];
    __shared__ float lmT[KD][33];
    __shared__ float tC[KD], uC[KD], tR[32], uR[32];
    __shared__ float red[256];

    const int tid = threadIdx.x;
    const int lane = tid & 63;
    const int wid = tid >> 6;
    const int wl = wid & 3, wi = wid >> 2;
    const int fr = lane & 15;
    const int kg = lane >> 4;

    if (tid < 256) {
        float e = (tid < KD) ? ea_g[b * KD + tid] : eb_g[b * KD + (tid - KD)];
        red[tid] = e;
    }
    __syncthreads();
    for (int s = 128; s > 0; s >>= 1) {
        if (tid < s) red[tid] = fmaxf(red[tid], red[tid + s]);
        __syncthreads();
    }
    const float is = 1.0f / red[0];
    const float* Ce = which ? eb_g : ea_g;
    const float* Re = which ? ea_g : eb_g;
    if (tid < KD) {
        float g = Ce[b * KD + tid] * is;
        float den = 1.0f / (g * g + 1.0f);
        tC[tid] = g * den; uC[tid] = den;
    } else if (tid < KD + 32) {
        int i = tid - KD;
        float g = Re[b * KD + i0 + i] * is;
        float den = 1.0f / (g * g + 1.0f);
        tR[i] = g * den; uR[i] = den;
    }
    __syncthreads();
    #pragma unroll
    for (int u = 0; u < 8; ++u) {
        int idx = tid + u * 512;
        int l = idx >> 5, i = idx & 31;
        float re = tR[i] - tC[l], im = uR[i] - uC[l];
        lmT[l][i] = LMB * (re * re + im * im);
    }

    // H planes: straight bf16x8 copies (pre-converted by invert)
    #pragma unroll
    for (int u = 0; u < 4; ++u) {
        int idx = tid + u * 512;                  // 2048 groups of 8 ushorts
        int row = idx >> 4, g8 = idx & 15;
        *(bf16x8*)&Hh[row][g8 * 8] = *(const bf16x8*)(Hg + (size_t)row * KD + g8 * 8);
        *(bf16x8*)&Hl[row][g8 * 8] = *(const bf16x8*)(Hg + (size_t)KD * KD + (size_t)row * KD + g8 * 8);
    }
    // W0[i][d] = r_i[d]
    if (which == 0) {
        #pragma unroll
        for (int u = 0; u < 2; ++u) {
            int idx4 = (tid + u * 512) * 4;
            int i = idx4 >> 7, d = idx4 & 127;
            f32x4 v = *(const f32x4*)(Rs + (size_t)(i0 + i) * KD + d);
            bf16x4 hv, lv;
            #pragma unroll
            for (int q = 0; q < 4; ++q) {
                ushort_t hh, ll;
                split_bf16(v[q], hh, ll);
                hv[q] = (short)hh; lv[q] = (short)ll;
            }
            *(bf16x4*)&Wh[i][d] = hv;
            *(bf16x4*)&Wl[i][d] = lv;
        }
    } else {
        #pragma unroll
        for (int u = 0; u < 8; ++u) {
            int idx = tid + u * 512;
            int i = idx & 31, d = idx >> 5;
            float v = Rs[(size_t)d * KD + i0 + i];
            ushort_t hh, ll;
            split_bf16(v, hh, ll);
            Wh[i][d] = hh; Wl[i][d] = ll;
        }
    }
    __syncthreads();

    f32x4 xacc[2];
    xacc[0] = (f32x4){0.f, 0.f, 0.f, 0.f};
    xacc[1] = (f32x4){0.f, 0.f, 0.f, 0.f};

    for (int t = 0; t < NTERMS; ++t) {
        f32x4 az[2];
        az[0] = (f32x4){0.f, 0.f, 0.f, 0.f};
        az[1] = (f32x4){0.f, 0.f, 0.f, 0.f};
        #pragma unroll
        for (int kk = 0; kk < 4; ++kk) {
            const int co = kk * 32 + kg * 8;
            bf16x8 Bh = *(const bf16x8*)&Wh[wi * 16 + fr][co];
            bf16x8 Bl = *(const bf16x8*)&Wl[wi * 16 + fr][co];
            #pragma unroll
            for (int mi = 0; mi < 2; ++mi) {
                const int rA = wl * 32 + mi * 16 + fr;
                bf16x8 Ah_ = *(const bf16x8*)&Hh[rA][co];
                bf16x8 Al_ = *(const bf16x8*)&Hl[rA][co];
                az[mi] = __builtin_amdgcn_mfma_f32_16x16x32_bf16(Ah_, Bh, az[mi], 0, 0, 0);
                az[mi] = __builtin_amdgcn_mfma_f32_16x16x32_bf16(Ah_, Bl, az[mi], 0, 0, 0);
                az[mi] = __builtin_amdgcn_mfma_f32_16x16x32_bf16(Al_, Bh, az[mi], 0, 0, 0);
            }
        }
        const float sg = (t & 1) ? -1.f : 1.f;
        #pragma unroll
        for (int mi = 0; mi < 2; ++mi) {
            xacc[mi][0] += sg * az[mi][0];
            xacc[mi][1] += sg * az[mi][1];
            xacc[mi][2] += sg * az[mi][2];
            xacc[mi][3] += sg * az[mi][3];
        }
        if (t + 1 < NTERMS) {
            __syncthreads();
            const int i = wi * 16 + fr;
            #pragma unroll
            for (int mi = 0; mi < 2; ++mi) {
                const int l0 = wl * 32 + mi * 16 + kg * 4;
                bf16x4 hv, lv;
                #pragma unroll
                for (int r = 0; r < 4; ++r) {
                    float w = lmT[l0 + r][i] * az[mi][r];
                    ushort_t hh, ll;
                    split_bf16(w, hh, ll);
                    hv[r] = (short)hh; lv[r] = (short)ll;
                }
                *(bf16x4*)&Wh[i][l0] = hv;
                *(bf16x4*)&Wl[i][l0] = lv;
            }
            __syncthreads();
        }
    }

    const int i = wi * 16 + fr;
    #pragma unroll
    for (int mi = 0; mi < 2; ++mi) {
        const int l0 = wl * 32 + mi * 16 + kg * 4;
        float4 o;
        o.x = xacc[mi][0]; o.y = xacc[mi][1]; o.z = xacc[mi][2]; o.w = xacc[mi][3];
        *(float4*)(op + (size_t)(i0 + i) * KD + l0) = o;
    }
}

extern "C" void kernel_launch(void* const* d_in, const int* in_sizes, int n_in,
                              void* d_out, int out_size, void* d_ws, size_t ws_size,
                              hipStream_t stream) {
    (void)in_sizes; (void)n_in; (void)out_size; (void)ws_size;
    const float* evals_a = (const float*)d_in[0];
    const float* pinv_a  = (const float*)d_in[1];
    const float* descr_a = (const float*)d_in[2];
    const float* evals_b = (const float*)d_in[3];
    const float* pinv_b  = (const float*)d_in[4];
    const float* descr_b = (const float*)d_in[5];
    float* out = (float*)d_out;
    float* ws = (float*)d_ws;

    const size_t SD = (size_t)BB * KD * DD;   // 524288
    const size_t MM = (size_t)BB * KD * KD;   // 262144
    float* sd_a  = ws;
    float* sd_b  = sd_a + SD;
    float* AA    = sd_b + SD;        // 3*MM: [0]=AA_aa [1]=AA_bb [2]=AA_ba
    ushort_t* Hbf = (ushort_t*)(AA + 3 * MM);  // 2*MM u16 pairs (4MB) in old H slot

    // zero sd (proj atomics) and AA (gram atomics)
    hipMemsetAsync(sd_a, 0, (2 * SD + 3 * MM) * sizeof(float), stream);
    proj_kernel<<<dim3(BB, 2, NSL), 1024, 0, stream>>>(pinv_a, descr_a, pinv_b, descr_b, sd_a, sd_b);
    gram_kernel<<<dim3(BB, 3, 4), 512, 0, stream>>>(sd_a, sd_b, AA);
    invert_kernel<<<dim3(BB, 2), 512, 0, stream>>>(AA, Hbf);
    solve_kernel<<<dim3(BB, 4, 2), 512, 0, stream>>>(AA + 2 * MM, evals_a, evals_b, Hbf, out);
}